// Round 10
// baseline (273.007 us; speedup 1.0000x reference)
//
#include <hip/hip_runtime.h>
#include <hip/hip_bf16.h>

// ---------------- problem constants ----------------
constexpr int NV = 16384;   // 16*1024 z vectors
constexpr int D  = 128;     // embed dim
constexpr int NE = 8192;    // codebook size
constexpr float DECAY = 0.99f;
constexpr float BETA  = 1.0f;
constexpr float EPS   = 1e-5f;
constexpr float LO_SCALE     = 4096.0f;        // 2^12: keeps f16 lo-part normal
constexpr float INV_LO_SCALE = 1.0f / 4096.0f;

// distance-kernel geometry
constexpr int Q = 8;                       // code slices (grid.x -> XCD affinity)
constexpr int CODES_PER_Q = NE / Q;        // 1024
constexpr int BZ = 256;                    // z rows per block (4 waves x 64 rows)
constexpr int NCAND = Q * 2;               // refine candidates per row (16)

// ---------------- ws layout (float units) ----------------
constexpr size_t WS_Z2    = 0;                            // NV x 256 f16 = NV*128 floats
constexpr size_t WS_E2    = WS_Z2 + (size_t)NV * 128;     // NE x 256 f16 = NE*128 floats
constexpr size_t WS_EN2   = WS_E2 + (size_t)NE * 128;     // NE (fp32, round-1 replica)
constexpr size_t WS_MINI2 = WS_EN2 + NE;                  // NV*NCAND (int)
// aliases over z2 region (z2 dead once k_dist finishes)
constexpr size_t WS_BINS  = WS_Z2;                        // NE
constexpr size_t WS_ESUM  = WS_BINS + NE;                 // NE*D
constexpr size_t WS_LPART = WS_ESUM + (size_t)NE * D;     // 4096

// ---------------- out layout (float units) ----------------
constexpr size_t OUT_ZQ   = 0;                         // NV*D
constexpr size_t OUT_LOSS = OUT_ZQ + (size_t)NV*D;     // 1
constexpr size_t OUT_IDX  = OUT_LOSS + 1;              // NV
constexpr size_t OUT_EMB  = OUT_IDX + NV;              // NE*D
constexpr size_t OUT_CS   = OUT_EMB + (size_t)NE*D;    // NE
constexpr size_t OUT_EAVG = OUT_CS + NE;               // NE*D

using half8  = __attribute__((ext_vector_type(8))) _Float16;
using half2v = __attribute__((ext_vector_type(2))) _Float16;
using f32x4  = __attribute__((ext_vector_type(4))) float;

__device__ inline float waveReduceSum(float v) {
    #pragma unroll
    for (int o = 32; o > 0; o >>= 1) v += __shfl_xor(v, o, 64);
    return v;
}

// ---------- fused prep: z rows (normalize + split) and emb rows (split + |e|^2) ----------
// blocks 0..NV/4-1: z path (bitwise = R1 k_norm_z math); blocks NV/4..: e path.
__global__ void k_prep(const float* __restrict__ z, const float* __restrict__ emb,
                       _Float16* __restrict__ z2, _Float16* __restrict__ e2,
                       float* __restrict__ en2) {
    int tid = threadIdx.x;
    int l = tid & 63;
    int g = blockIdx.x * 4 + (tid >> 6);
    bool isZ = g < NV;
    int row = isZ ? g : g - NV;
    const float* src = isZ ? &z[(size_t)row * D] : &emb[(size_t)row * D];
    _Float16* dst = isZ ? &z2[(size_t)row * 256] : &e2[(size_t)row * 256];

    const float2 v = *reinterpret_cast<const float2*>(&src[l * 2]);
    float s = waveReduceSum(v.x * v.x + v.y * v.y);
    float x0 = v.x, x1 = v.y;
    if (isZ) {
        float inv = 1.0f / fmaxf(sqrtf(s), 1e-12f);
        x0 *= inv; x1 *= inv;
    } else {
        if (l == 0) en2[row] = s;   // bitwise = round-1 k_enorm2
    }
    _Float16 h0 = (_Float16)x0, h1 = (_Float16)x1;
    _Float16 l0 = (_Float16)((x0 - (float)h0) * LO_SCALE);
    _Float16 l1 = (_Float16)((x1 - (float)h1) * LO_SCALE);
    half2v hh = {h0, h1}, lv = {l0, l1};
    *reinterpret_cast<half2v*>(&dst[l * 2])       = hh;
    *reinterpret_cast<half2v*>(&dst[128 + l * 2]) = lv;
}

// ---------- MFMA approximate distance + top-2 per (row, slice) ----------
// BARRIER-FREE: no LDS, no __syncthreads. 256 thr = 4 independent waves; each wave
// owns 64 z rows (rf=4; A hi/lo K=256 in 64 VGPRs) and streams B-fragments for its
// 1024-code slice DIRECTLY from global (e2 is L2-resident; grid.x=q => XCD q caches
// exactly its 512 KB quarter). Per 16-code colfrag: 8 global b128 loads (imm offsets
// off a per-lane base) + 48 MFMA in 12 independent chains + R7-exact top-2 fold.
// dot ~= accA + (accB1+accB2)/4096 (err ~5e-7); re-ranked by fp32 replica in k_gather.
__global__ __launch_bounds__(256, 2) void k_dist(
        const _Float16* __restrict__ z2, const _Float16* __restrict__ e2,
        const float* __restrict__ en2, int* __restrict__ minI2) {
    const int tid = threadIdx.x;
    const int w  = tid >> 6;
    const int l  = tid & 63;
    const int lg = l >> 4;      // k-group (0..3)
    const int ll = l & 15;      // low lane: A-row / B-col index
    const int q  = blockIdx.x;
    const int zb = blockIdx.y * BZ;
    const int cbase0 = q * CODES_PER_Q;

    // A fragments: a[rowfrag][kfrag], k = kf*32 + lg*8 + j (same convention as B)
    half8 a[4][8];
    #pragma unroll
    for (int rf = 0; rf < 4; ++rf) {
        const size_t row = (size_t)(zb + w * 64 + rf * 16 + ll);
        #pragma unroll
        for (int kf = 0; kf < 8; ++kf)
            a[rf][kf] = *reinterpret_cast<const half8*>(&z2[row * 256 + kf * 32 + lg * 8]);
    }

    // per-lane B base: code (cbase0+ll) row, k-slot lg*8 (halfs); colfrag adds 4096 halfs
    const _Float16* bp = e2 + (size_t)(cbase0 + ll) * 256 + lg * 8;
    const float*    ep = en2 + cbase0 + ll;

    float bV1[16], bV2[16];
    int   bI1[16], bI2[16];
    #pragma unroll
    for (int i = 0; i < 16; ++i) { bV1[i] = 3.4e38f; bV2[i] = 3.4e38f; bI1[i] = 0; bI2[i] = 0; }

    for (int cf = 0; cf < CODES_PER_Q / 16; ++cf) {
        const _Float16* bc = bp + (size_t)cf * 4096;
        const float e2v = ep[cf * 16];
        const int code = cbase0 + cf * 16 + ll;

        f32x4 accA[4], accB1[4], accB2[4];
        #pragma unroll
        for (int rf = 0; rf < 4; ++rf) {
            accA[rf]  = f32x4{0.f, 0.f, 0.f, 0.f};
            accB1[rf] = f32x4{0.f, 0.f, 0.f, 0.f};
            accB2[rf] = f32x4{0.f, 0.f, 0.f, 0.f};
        }
        #pragma unroll
        for (int kq = 0; kq < 4; ++kq) {
            half8 bh = *reinterpret_cast<const half8*>(bc + kq * 32);        // hi k-slots
            half8 bl = *reinterpret_cast<const half8*>(bc + kq * 32 + 128);  // lo k-slots
            // 12 independent chains, round-robin: reuse distance 12 issues
            accA[0]  = __builtin_amdgcn_mfma_f32_16x16x32_f16(a[0][kq],     bh, accA[0],  0, 0, 0);
            accA[1]  = __builtin_amdgcn_mfma_f32_16x16x32_f16(a[1][kq],     bh, accA[1],  0, 0, 0);
            accA[2]  = __builtin_amdgcn_mfma_f32_16x16x32_f16(a[2][kq],     bh, accA[2],  0, 0, 0);
            accA[3]  = __builtin_amdgcn_mfma_f32_16x16x32_f16(a[3][kq],     bh, accA[3],  0, 0, 0);
            accB1[0] = __builtin_amdgcn_mfma_f32_16x16x32_f16(a[0][kq + 4], bh, accB1[0], 0, 0, 0);
            accB1[1] = __builtin_amdgcn_mfma_f32_16x16x32_f16(a[1][kq + 4], bh, accB1[1], 0, 0, 0);
            accB1[2] = __builtin_amdgcn_mfma_f32_16x16x32_f16(a[2][kq + 4], bh, accB1[2], 0, 0, 0);
            accB1[3] = __builtin_amdgcn_mfma_f32_16x16x32_f16(a[3][kq + 4], bh, accB1[3], 0, 0, 0);
            accB2[0] = __builtin_amdgcn_mfma_f32_16x16x32_f16(a[0][kq],     bl, accB2[0], 0, 0, 0);
            accB2[1] = __builtin_amdgcn_mfma_f32_16x16x32_f16(a[1][kq],     bl, accB2[1], 0, 0, 0);
            accB2[2] = __builtin_amdgcn_mfma_f32_16x16x32_f16(a[2][kq],     bl, accB2[2], 0, 0, 0);
            accB2[3] = __builtin_amdgcn_mfma_f32_16x16x32_f16(a[3][kq],     bl, accB2[3], 0, 0, 0);
        }
        #pragma unroll
        for (int rf = 0; rf < 4; ++rf) {
            #pragma unroll
            for (int r = 0; r < 4; ++r) {
                float b12 = accB1[rf][r] + accB2[rf][r];
                float dot = fmaf(b12, INV_LO_SCALE, accA[rf][r]);
                float s = fmaf(-2.0f, dot, e2v);
                int bi = rf * 4 + r;
                // branchless top-2 insert (R7-exact semantics)
                bool c1 = s < bV1[bi];
                float sv = c1 ? bV1[bi] : s;
                int   si = c1 ? bI1[bi] : code;
                bV1[bi] = c1 ? s    : bV1[bi];
                bI1[bi] = c1 ? code : bI1[bi];
                bool c2 = sv < bV2[bi];
                bV2[bi] = c2 ? sv : bV2[bi];
                bI2[bi] = c2 ? si : bI2[bi];
            }
        }
    }

    // cross-lane top-2 merge over the 16 ll lanes (disjoint code sets per step)
    #pragma unroll
    for (int bi = 0; bi < 16; ++bi) {
        float v1 = bV1[bi], v2 = bV2[bi];
        int   i1 = bI1[bi], i2 = bI2[bi];
        #pragma unroll
        for (int m = 1; m < 16; m <<= 1) {
            float w1 = __shfl_xor(v1, m, 64);
            int   j1 = __shfl_xor(i1, m, 64);
            float w2 = __shfl_xor(v2, m, 64);
            int   j2 = __shfl_xor(i2, m, 64);
            bool oth = (w1 < v1) || (w1 == v1 && j1 < i1);
            if (oth) {
                bool keep = (v1 < w2) || (v1 == w2 && i1 < j2);
                v2 = keep ? v1 : w2; i2 = keep ? i1 : j2;
                v1 = w1; i1 = j1;
            } else {
                bool repl = (w1 < v2) || (w1 == v2 && j1 < i2);
                v2 = repl ? w1 : v2; i2 = repl ? j1 : i2;
            }
        }
        if (ll == 0) {
            int rf = bi >> 2, r = bi & 3;
            int zrow = zb + w * 64 + rf * 16 + lg * 4 + r;   // C/D: row=(lane>>4)*4+reg
            size_t o = ((size_t)zrow * Q + q) * 2;
            minI2[o] = i1; minI2[o + 1] = i2;
        }
    }
}

// ---------- round-1-replica fp32 refine over 16 candidates + gather + loss + segsums ----------
__global__ void k_gather(const float* __restrict__ z, const float* __restrict__ emb,
                         const float* __restrict__ en2, const int* __restrict__ minI2,
                         float* __restrict__ outZq, float* __restrict__ outIdx,
                         float* __restrict__ bins, float* __restrict__ esum,
                         float* __restrict__ lossPart) {
    __shared__ float zsh[4][128];
    int tid = threadIdx.x;
    int wave = tid >> 6, lane = tid & 63;
    int zr = blockIdx.x * 4 + wave;

    // zn exactly as round-1 k_norm_z (fp32 butterfly, same ops)
    const float2 zv = *reinterpret_cast<const float2*>(&z[(size_t)zr * D + lane * 2]);
    float s = waveReduceSum(zv.x * zv.x + zv.y * zv.y);
    float inv = 1.0f / fmaxf(sqrtf(s), 1e-12f);
    float znx = zv.x * inv, zny = zv.y * inv;
    zsh[wave][lane * 2]     = znx;
    zsh[wave][lane * 2 + 1] = zny;
    __syncthreads();

    // 16 lanes re-score the 16 candidates with round-1's exact arithmetic:
    // sequential fmaf chain k=0..127, then s = fmaf(-2, dot, en2[c]).
    float cv = 3.4e38f; int ci = 0x7fffffff;
    if (lane < NCAND) {
        ci = minI2[(size_t)zr * NCAND + lane];
        const float* er = &emb[(size_t)ci * D];
        float dot = 0.0f;
        #pragma unroll 8
        for (int k = 0; k < 128; ++k) dot = fmaf(zsh[wave][k], er[k], dot);
        cv = fmaf(-2.0f, dot, en2[ci]);
    }
    float bv = cv; int bi = ci;
    #pragma unroll
    for (int m = 1; m < NCAND; m <<= 1) {
        float ov = __shfl_xor(bv, m, 64);
        int   oi = __shfl_xor(bi, m, 64);
        if (ov < bv || (ov == bv && oi < bi)) { bv = ov; bi = oi; }
    }
    bi = __shfl(bi, 0, 64);    // broadcast winner to all 64 lanes
    if (lane == 0) outIdx[zr] = (float)bi;

    float2 e = *reinterpret_cast<const float2*>(&emb[(size_t)bi * D + lane * 2]);
    *reinterpret_cast<float2*>(&outZq[(size_t)zr * D + lane * 2]) = e;

    float dx = e.x - znx, dy = e.y - zny;
    float ls = waveReduceSum(dx * dx + dy * dy);

    if (lane == 0) atomicAdd(&bins[bi], 1.0f);
    atomicAdd(&esum[(size_t)bi * D + lane * 2 + 0], znx);
    atomicAdd(&esum[(size_t)bi * D + lane * 2 + 1], zny);

    __shared__ float part[4];
    if (lane == 0) part[wave] = ls;
    __syncthreads();
    if (tid == 0) lossPart[blockIdx.x] = (part[0] + part[1]) + (part[2] + part[3]);
}

// ---------- per-code EMA update + renormalize; block 0 also reduces the loss ----------
__global__ void k_codebook(const float* __restrict__ emb, const float* __restrict__ csz,
                           const float* __restrict__ eavg, const float* __restrict__ bins,
                           const float* __restrict__ esum, const float* __restrict__ lossPart,
                           float* __restrict__ outEmb, float* __restrict__ outCs,
                           float* __restrict__ outEavg, float* __restrict__ outLoss) {
    int tid = threadIdx.x;
    int wave = tid >> 6, lane = tid & 63;
    int n = blockIdx.x * 4 + wave;

    if (blockIdx.x == 0) {               // fold former k_loss here (block-uniform branch)
        float s = 0.0f;
        for (int i = tid; i < 4096; i += 256) s += lossPart[i];
        s = waveReduceSum(s);
        __shared__ float p[4];
        if ((tid & 63) == 0) p[tid >> 6] = s;
        __syncthreads();
        if (tid == 0) outLoss[0] = BETA * ((p[0] + p[1]) + (p[2] + p[3])) / (float)((size_t)NV * D);
    }

    float b = bins[n];
    if (lane == 0) outCs[n] = csz[n] * DECAY + (1.0f - DECAY) * b;

    float2 es = *reinterpret_cast<const float2*>(&esum[(size_t)n * D + lane * 2]);
    float invb = 1.0f / (b + EPS);
    float mx = es.x * invb, my = es.y * invb;
    float ss = waveReduceSum(mx * mx + my * my);
    float invn = 1.0f / fmaxf(sqrtf(ss), 1e-12f);

    float2 er = *reinterpret_cast<const float2*>(&emb[(size_t)n * D + lane * 2]);
    float enx = (b == 0.0f) ? er.x : mx * invn;
    float eny = (b == 0.0f) ? er.y : my * invn;

    float2 ea = *reinterpret_cast<const float2*>(&eavg[(size_t)n * D + lane * 2]);
    float nax = ea.x * DECAY + (1.0f - DECAY) * enx;
    float nay = ea.y * DECAY + (1.0f - DECAY) * eny;
    float2 no; no.x = nax; no.y = nay;
    *reinterpret_cast<float2*>(&outEavg[(size_t)n * D + lane * 2]) = no;

    float ss2 = waveReduceSum(nax * nax + nay * nay);
    float inv2 = 1.0f / fmaxf(sqrtf(ss2), 1e-12f);
    float2 ne; ne.x = nax * inv2; ne.y = nay * inv2;
    *reinterpret_cast<float2*>(&outEmb[(size_t)n * D + lane * 2]) = ne;
}

extern "C" void kernel_launch(void* const* d_in, const int* in_sizes, int n_in,
                              void* d_out, int out_size, void* d_ws, size_t ws_size,
                              hipStream_t stream) {
    (void)in_sizes; (void)n_in; (void)out_size; (void)ws_size;
    const float* z    = (const float*)d_in[0];
    const float* emb  = (const float*)d_in[1];
    const float* csz  = (const float*)d_in[2];
    const float* eavg = (const float*)d_in[3];
    float* out = (float*)d_out;
    float* ws  = (float*)d_ws;

    _Float16* z2   = (_Float16*)(ws + WS_Z2);
    _Float16* e2   = (_Float16*)(ws + WS_E2);
    float*  en2    = ws + WS_EN2;
    int*    minI2  = (int*)(ws + WS_MINI2);
    float*  bins   = ws + WS_BINS;
    float*  esum   = ws + WS_ESUM;
    float*  lpart  = ws + WS_LPART;

    k_prep<<<(NV + NE) / 4, 256, 0, stream>>>(z, emb, z2, e2, en2);
    // grid.x = q (8) so blockId%8 == q: each XCD's L2 caches one 512 KB e2 quarter
    k_dist<<<dim3(Q, NV / BZ), 256, 0, stream>>>(z2, e2, en2, minI2);
    // bins+esum zeroing must follow k_dist (they alias the z2 region)
    hipMemsetAsync(bins, 0, ((size_t)NE + (size_t)NE * D) * sizeof(float), stream);
    k_gather<<<NV / 4, 256, 0, stream>>>(z, emb, en2, minI2,
                                         out + OUT_ZQ, out + OUT_IDX, bins, esum, lpart);
    k_codebook<<<NE / 4, 256, 0, stream>>>(emb, csz, eavg, bins, esum, lpart,
                                           out + OUT_EMB, out + OUT_CS, out + OUT_EAVG,
                                           out + OUT_LOSS);
}

// Round 11
// 169.179 us; speedup vs baseline: 1.6137x; 1.6137x over previous
//
#include <hip/hip_runtime.h>
#include <hip/hip_bf16.h>

// ---------------- problem constants ----------------
constexpr int NV = 16384;   // 16*1024 z vectors
constexpr int D  = 128;     // embed dim
constexpr int NE = 8192;    // codebook size
constexpr float DECAY = 0.99f;
constexpr float BETA  = 1.0f;
constexpr float EPS   = 1e-5f;
constexpr float LO_SCALE     = 4096.0f;        // 2^12: keeps f16 lo-part normal
constexpr float INV_LO_SCALE = 1.0f / 4096.0f;

// packed-screen quantization: u = (u32(s*65536 + 98304) << 13) | code
// s = |e|^2 - 2*dot  in [-1.001, 3.001]  ->  t in [~32K, ~295K] < 2^19  (13 code bits spare)
constexpr float QSCALE = 65536.0f;
constexpr float QOFF   = 98304.0f;

// distance-kernel geometry
constexpr int Q = 8;                       // code slices (grid.y)
constexpr int CODES_PER_Q = NE / Q;        // 1024
constexpr int TILE_C = 32;                 // codes per LDS tile
constexpr int TILES = CODES_PER_Q / TILE_C;// 32
constexpr int BZ = 128;                    // z rows per block (4 waves x 32 rows)
constexpr int NCAND = Q * 2;               // refine candidates per row (16)

// ---------------- ws layout (float units) ----------------
constexpr size_t WS_Z2    = 0;                            // NV x 256 f16 = NV*128 floats
constexpr size_t WS_E2    = WS_Z2 + (size_t)NV * 128;     // NE x 256 f16 = NE*128 floats
constexpr size_t WS_EN2   = WS_E2 + (size_t)NE * 128;     // NE (fp32, round-1 replica)
constexpr size_t WS_MINI2 = WS_EN2 + NE;                  // NV*NCAND (u32 packed)
// aliases over z2 region (z2 dead once k_dist finishes)
constexpr size_t WS_BINS  = WS_Z2;                        // NE
constexpr size_t WS_ESUM  = WS_BINS + NE;                 // NE*D
constexpr size_t WS_LPART = WS_ESUM + (size_t)NE * D;     // 4096

// ---------------- out layout (float units) ----------------
constexpr size_t OUT_ZQ   = 0;                         // NV*D
constexpr size_t OUT_LOSS = OUT_ZQ + (size_t)NV*D;     // 1
constexpr size_t OUT_IDX  = OUT_LOSS + 1;              // NV
constexpr size_t OUT_EMB  = OUT_IDX + NV;              // NE*D
constexpr size_t OUT_CS   = OUT_EMB + (size_t)NE*D;    // NE
constexpr size_t OUT_EAVG = OUT_CS + NE;               // NE*D

using half8  = __attribute__((ext_vector_type(8))) _Float16;
using half2v = __attribute__((ext_vector_type(2))) _Float16;
using f32x4  = __attribute__((ext_vector_type(4))) float;

__device__ inline float waveReduceSum(float v) {
    #pragma unroll
    for (int o = 32; o > 0; o >>= 1) v += __shfl_xor(v, o, 64);
    return v;
}
__device__ inline unsigned umin32(unsigned a, unsigned b) { return a < b ? a : b; }
__device__ inline unsigned umax32(unsigned a, unsigned b) { return a > b ? a : b; }

// async global->LDS, 16B per lane; LDS dest = wave-uniform base + lane*16 (linear)
__device__ inline void gload_lds16(const void* g, void* s) {
    __builtin_amdgcn_global_load_lds(
        (const __attribute__((address_space(1))) unsigned int*)g,
        (__attribute__((address_space(3))) unsigned int*)s, 16, 0, 0);
}

// ---------- fused prep: z rows (normalize + split) and emb rows (split + |e|^2) ----------
// blocks 0..NV/4-1: z path (bitwise = R1 k_norm_z math); blocks NV/4..: e path.
__global__ void k_prep(const float* __restrict__ z, const float* __restrict__ emb,
                       _Float16* __restrict__ z2, _Float16* __restrict__ e2,
                       float* __restrict__ en2) {
    int tid = threadIdx.x;
    int l = tid & 63;
    int g = blockIdx.x * 4 + (tid >> 6);
    bool isZ = g < NV;
    int row = isZ ? g : g - NV;
    const float* src = isZ ? &z[(size_t)row * D] : &emb[(size_t)row * D];
    _Float16* dst = isZ ? &z2[(size_t)row * 256] : &e2[(size_t)row * 256];

    const float2 v = *reinterpret_cast<const float2*>(&src[l * 2]);
    float s = waveReduceSum(v.x * v.x + v.y * v.y);
    float x0 = v.x, x1 = v.y;
    if (isZ) {
        float inv = 1.0f / fmaxf(sqrtf(s), 1e-12f);
        x0 *= inv; x1 *= inv;
    } else {
        if (l == 0) en2[row] = s;   // bitwise = round-1 k_enorm2
    }
    _Float16 h0 = (_Float16)x0, h1 = (_Float16)x1;
    _Float16 l0 = (_Float16)((x0 - (float)h0) * LO_SCALE);
    _Float16 l1 = (_Float16)((x1 - (float)h1) * LO_SCALE);
    half2v hh = {h0, h1}, lv = {l0, l1};
    *reinterpret_cast<half2v*>(&dst[l * 2])       = hh;
    *reinterpret_cast<half2v*>(&dst[128 + l * 2]) = lv;
}

// ---------- MFMA approximate distance + packed-u32 top-2 per (row, slice) ----------
// R7-proven structure: 256 thr = 4 waves; wave owns 32 z rows (2 rowfrags); A hi/lo
// K=256 in regs; e-tiles (32 codes x 256 k) double-buffered via global_load_lds with
// pre-swizzled source (XOR involution); 6 independent MFMA chains.
// NEW: distances quantized to 19 bits and packed with the 13-bit code ->
// top-2 insert = min/max/min on u32 (2 regs/slot), first-index ties preserved
// (lower code wins on equal quantized distance). Candidates re-ranked by the
// R1-replica fp32 arbiter in k_gather, which covers the ~1.6e-5 quant noise.
__global__ __launch_bounds__(256, 2) void k_dist(
        const _Float16* __restrict__ z2, const _Float16* __restrict__ e2,
        const float* __restrict__ en2, unsigned* __restrict__ minI2) {
    __shared__ _Float16 eb[2][TILE_C * 256];   // 2 x 16 KB
    __shared__ float c0s[CODES_PER_Q];         // 4 KB: prequantized e2-norm constants

    const int tid = threadIdx.x;
    const int w  = tid >> 6;
    const int l  = tid & 63;
    const int lg = l >> 4;      // k-group (0..3)
    const int ll = l & 15;      // low lane: A-row / B-col index
    const int zb = blockIdx.x * BZ;
    const int q  = blockIdx.y;
    const int cbase0 = q * CODES_PER_Q;

    // A fragments: a[rowfrag][kfrag], k = kf*32 + lg*8 + j (same convention as B)
    half8 a[2][8];
    #pragma unroll
    for (int rf = 0; rf < 2; ++rf) {
        const size_t row = (size_t)(zb + w * 32 + rf * 16 + ll);
        #pragma unroll
        for (int kf = 0; kf < 8; ++kf)
            a[rf][kf] = *reinterpret_cast<const half8*>(&z2[row * 256 + kf * 32 + lg * 8]);
    }

    // prequantized constant: c0 = |e|^2 * QSCALE + QOFF
    for (int i = tid; i < CODES_PER_Q; i += 256)
        c0s[i] = fmaf(en2[cbase0 + i], QSCALE, QOFF);

    // stage tile t into buffer b: 1024 16B-chunks; wave w call i covers chunks
    // (w*4+i)*64 + lane. LDS linear; global src pre-swizzled (j ^= row&7).
    auto stage = [&](int b, int t) {
        const char* tbase = reinterpret_cast<const char*>(&e2[(size_t)(cbase0 + t * TILE_C) * 256]);
        #pragma unroll
        for (int i = 0; i < 4; ++i) {
            int c = (w * 4 + i) * 64 + l;
            int row = c >> 5, j = c & 31;
            const char* src = tbase + row * 512 + ((j ^ (row & 7)) * 16);
            gload_lds16(src, &eb[b][(size_t)(w * 4 + i) * 512]);
        }
    };

    stage(0, 0);

    unsigned bU1[8], bU2[8];
    #pragma unroll
    for (int i = 0; i < 8; ++i) { bU1[i] = 0xFFFFFFFFu; bU2[i] = 0xFFFFFFFFu; }

    int cur = 0;
    for (int t = 0; t < TILES; ++t) {
        __syncthreads();                       // vmcnt drained: eb[cur] staged & visible
        if (t + 1 < TILES) stage(cur ^ 1, t + 1);   // async prefetch into other buffer

        const char* base = reinterpret_cast<const char*>(&eb[cur][0]);
        #pragma unroll
        for (int n = 0; n < 2; ++n) {          // colfrag: 16 codes each
            f32x4 accA[2], accB1[2], accB2[2];
            #pragma unroll
            for (int rf = 0; rf < 2; ++rf) {
                accA[rf]  = f32x4{0.f, 0.f, 0.f, 0.f};
                accB1[rf] = f32x4{0.f, 0.f, 0.f, 0.f};
                accB2[rf] = f32x4{0.f, 0.f, 0.f, 0.f};
            }
            const int brow = n * 16 + ll;
            const char* rbase = base + brow * 512;
            const int swz = brow & 7;
            #pragma unroll
            for (int kq = 0; kq < 4; ++kq) {
                half8 bh = *reinterpret_cast<const half8*>(rbase + (((kq * 4 + lg) ^ swz) * 16));
                half8 bl = *reinterpret_cast<const half8*>(rbase + ((((kq + 4) * 4 + lg) ^ swz) * 16));
                // round-robin over 6 independent chains: reuse distance 6 issues
                accA[0]  = __builtin_amdgcn_mfma_f32_16x16x32_f16(a[0][kq],     bh, accA[0],  0, 0, 0);
                accA[1]  = __builtin_amdgcn_mfma_f32_16x16x32_f16(a[1][kq],     bh, accA[1],  0, 0, 0);
                accB1[0] = __builtin_amdgcn_mfma_f32_16x16x32_f16(a[0][kq + 4], bh, accB1[0], 0, 0, 0);
                accB1[1] = __builtin_amdgcn_mfma_f32_16x16x32_f16(a[1][kq + 4], bh, accB1[1], 0, 0, 0);
                accB2[0] = __builtin_amdgcn_mfma_f32_16x16x32_f16(a[0][kq],     bl, accB2[0], 0, 0, 0);
                accB2[1] = __builtin_amdgcn_mfma_f32_16x16x32_f16(a[1][kq],     bl, accB2[1], 0, 0, 0);
            }
            const unsigned code = (unsigned)(cbase0 + t * TILE_C + n * 16 + ll);
            const float c0 = c0s[t * TILE_C + n * 16 + ll];
            #pragma unroll
            for (int rf = 0; rf < 2; ++rf) {
                #pragma unroll
                for (int r = 0; r < 4; ++r) {
                    // t = (|e|^2 - 2*(accA + (accB1+accB2)/4096)) * QSCALE + QOFF
                    //   = c0 - 2*QSCALE*accA - (2*QSCALE/4096)*b12
                    float b12 = accB1[rf][r] + accB2[rf][r];
                    float tq  = fmaf(-2.0f * QSCALE, accA[rf][r], c0);
                    tq = fmaf(-2.0f * QSCALE * INV_LO_SCALE, b12, tq);
                    unsigned u = ((unsigned)tq << 13) | code;   // cvt + lshl_or
                    int bi = rf * 4 + r;
                    unsigned m1 = bU1[bi];
                    bU2[bi] = umin32(umax32(u, m1), bU2[bi]);   // second-min
                    bU1[bi] = umin32(u, m1);
                }
            }
        }
        cur ^= 1;
    }

    // cross-lane top-2 merge over the 16 ll lanes (disjoint code sets; u unique)
    #pragma unroll
    for (int bi = 0; bi < 8; ++bi) {
        unsigned u1 = bU1[bi], u2 = bU2[bi];
        #pragma unroll
        for (int m = 1; m < 16; m <<= 1) {
            unsigned o1 = (unsigned)__shfl_xor((int)u1, m, 64);
            unsigned o2 = (unsigned)__shfl_xor((int)u2, m, 64);
            unsigned hi = umax32(u1, o1);
            u1 = umin32(u1, o1);
            u2 = umin32(umin32(u2, o2), hi);
        }
        if (ll == 0) {
            int rf = bi >> 2, r = bi & 3;
            int zrow = zb + w * 32 + rf * 16 + lg * 4 + r;   // C/D: row=(lane>>4)*4+reg
            size_t o = ((size_t)zrow * Q + q) * 2;
            minI2[o] = u1; minI2[o + 1] = u2;
        }
    }
}

// ---------- round-1-replica fp32 refine over 16 candidates + gather + loss + segsums ----------
__global__ void k_gather(const float* __restrict__ z, const float* __restrict__ emb,
                         const float* __restrict__ en2, const unsigned* __restrict__ minI2,
                         float* __restrict__ outZq, float* __restrict__ outIdx,
                         float* __restrict__ bins, float* __restrict__ esum,
                         float* __restrict__ lossPart) {
    __shared__ float zsh[4][128];
    int tid = threadIdx.x;
    int wave = tid >> 6, lane = tid & 63;
    int zr = blockIdx.x * 4 + wave;

    // zn exactly as round-1 k_norm_z (fp32 butterfly, same ops)
    const float2 zv = *reinterpret_cast<const float2*>(&z[(size_t)zr * D + lane * 2]);
    float s = waveReduceSum(zv.x * zv.x + zv.y * zv.y);
    float inv = 1.0f / fmaxf(sqrtf(s), 1e-12f);
    float znx = zv.x * inv, zny = zv.y * inv;
    zsh[wave][lane * 2]     = znx;
    zsh[wave][lane * 2 + 1] = zny;
    __syncthreads();

    // 16 lanes re-score the 16 candidates with round-1's exact arithmetic:
    // sequential fmaf chain k=0..127, then s = fmaf(-2, dot, en2[c]).
    float cv = 3.4e38f; int ci = 0x7fffffff;
    if (lane < NCAND) {
        ci = (int)(minI2[(size_t)zr * NCAND + lane] & 8191u);   // unpack code
        const float* er = &emb[(size_t)ci * D];
        float dot = 0.0f;
        #pragma unroll 8
        for (int k = 0; k < 128; ++k) dot = fmaf(zsh[wave][k], er[k], dot);
        cv = fmaf(-2.0f, dot, en2[ci]);
    }
    float bv = cv; int bi = ci;
    #pragma unroll
    for (int m = 1; m < NCAND; m <<= 1) {
        float ov = __shfl_xor(bv, m, 64);
        int   oi = __shfl_xor(bi, m, 64);
        if (ov < bv || (ov == bv && oi < bi)) { bv = ov; bi = oi; }
    }
    bi = __shfl(bi, 0, 64);    // broadcast winner to all 64 lanes
    if (lane == 0) outIdx[zr] = (float)bi;

    float2 e = *reinterpret_cast<const float2*>(&emb[(size_t)bi * D + lane * 2]);
    *reinterpret_cast<float2*>(&outZq[(size_t)zr * D + lane * 2]) = e;

    float dx = e.x - znx, dy = e.y - zny;
    float ls = waveReduceSum(dx * dx + dy * dy);

    if (lane == 0) atomicAdd(&bins[bi], 1.0f);
    atomicAdd(&esum[(size_t)bi * D + lane * 2 + 0], znx);
    atomicAdd(&esum[(size_t)bi * D + lane * 2 + 1], zny);

    __shared__ float part[4];
    if (lane == 0) part[wave] = ls;
    __syncthreads();
    if (tid == 0) lossPart[blockIdx.x] = (part[0] + part[1]) + (part[2] + part[3]);
}

// ---------- per-code EMA update + renormalize; block 0 also reduces the loss ----------
__global__ void k_codebook(const float* __restrict__ emb, const float* __restrict__ csz,
                           const float* __restrict__ eavg, const float* __restrict__ bins,
                           const float* __restrict__ esum, const float* __restrict__ lossPart,
                           float* __restrict__ outEmb, float* __restrict__ outCs,
                           float* __restrict__ outEavg, float* __restrict__ outLoss) {
    int tid = threadIdx.x;
    int wave = tid >> 6, lane = tid & 63;
    int n = blockIdx.x * 4 + wave;

    if (blockIdx.x == 0) {               // fold former k_loss here (block-uniform branch)
        float s = 0.0f;
        for (int i = tid; i < 4096; i += 256) s += lossPart[i];
        s = waveReduceSum(s);
        __shared__ float p[4];
        if ((tid & 63) == 0) p[tid >> 6] = s;
        __syncthreads();
        if (tid == 0) outLoss[0] = BETA * ((p[0] + p[1]) + (p[2] + p[3])) / (float)((size_t)NV * D);
    }

    float b = bins[n];
    if (lane == 0) outCs[n] = csz[n] * DECAY + (1.0f - DECAY) * b;

    float2 es = *reinterpret_cast<const float2*>(&esum[(size_t)n * D + lane * 2]);
    float invb = 1.0f / (b + EPS);
    float mx = es.x * invb, my = es.y * invb;
    float ss = waveReduceSum(mx * mx + my * my);
    float invn = 1.0f / fmaxf(sqrtf(ss), 1e-12f);

    float2 er = *reinterpret_cast<const float2*>(&emb[(size_t)n * D + lane * 2]);
    float enx = (b == 0.0f) ? er.x : mx * invn;
    float eny = (b == 0.0f) ? er.y : my * invn;

    float2 ea = *reinterpret_cast<const float2*>(&eavg[(size_t)n * D + lane * 2]);
    float nax = ea.x * DECAY + (1.0f - DECAY) * enx;
    float nay = ea.y * DECAY + (1.0f - DECAY) * eny;
    float2 no; no.x = nax; no.y = nay;
    *reinterpret_cast<float2*>(&outEavg[(size_t)n * D + lane * 2]) = no;

    float ss2 = waveReduceSum(nax * nax + nay * nay);
    float inv2 = 1.0f / fmaxf(sqrtf(ss2), 1e-12f);
    float2 ne; ne.x = nax * inv2; ne.y = nay * inv2;
    *reinterpret_cast<float2*>(&outEmb[(size_t)n * D + lane * 2]) = ne;
}

extern "C" void kernel_launch(void* const* d_in, const int* in_sizes, int n_in,
                              void* d_out, int out_size, void* d_ws, size_t ws_size,
                              hipStream_t stream) {
    (void)in_sizes; (void)n_in; (void)out_size; (void)ws_size;
    const float* z    = (const float*)d_in[0];
    const float* emb  = (const float*)d_in[1];
    const float* csz  = (const float*)d_in[2];
    const float* eavg = (const float*)d_in[3];
    float* out = (float*)d_out;
    float* ws  = (float*)d_ws;

    _Float16* z2   = (_Float16*)(ws + WS_Z2);
    _Float16* e2   = (_Float16*)(ws + WS_E2);
    float*    en2  = ws + WS_EN2;
    unsigned* minI2 = (unsigned*)(ws + WS_MINI2);
    float*  bins   = ws + WS_BINS;
    float*  esum   = ws + WS_ESUM;
    float*  lpart  = ws + WS_LPART;

    k_prep<<<(NV + NE) / 4, 256, 0, stream>>>(z, emb, z2, e2, en2);
    k_dist<<<dim3(NV / BZ, Q), 256, 0, stream>>>(z2, e2, en2, minI2);
    // bins+esum zeroing must follow k_dist (they alias the z2 region)
    hipMemsetAsync(bins, 0, ((size_t)NE + (size_t)NE * D) * sizeof(float), stream);
    k_gather<<<NV / 4, 256, 0, stream>>>(z, emb, en2, minI2,
                                         out + OUT_ZQ, out + OUT_IDX, bins, esum, lpart);
    k_codebook<<<NE / 4, 256, 0, stream>>>(emb, csz, eavg, bins, esum, lpart,
                                           out + OUT_EMB, out + OUT_CS, out + OUT_EAVG,
                                           out + OUT_LOSS);
}